// Round 12
// baseline (10520.443 us; speedup 1.0000x reference)
//
#include <hip/hip_runtime.h>
#include <stddef.h>

typedef unsigned int u32;

#define TC 64        // timestep chunk
#define NCHUNK 8

__device__ __forceinline__ float sigmoidf_(float x) {
    return 1.0f / (1.0f + __expf(-x));
}
__device__ __forceinline__ float tanhf_(float x) {
    float ax = fabsf(x);
    float e = __expf(-2.0f * ax);
    float t = (1.0f - e) / (1.0f + e);
    return copysignf(t, x);
}

// ---- per-access coherent (IF$-level) ops ----
__device__ __forceinline__ void ldg_cv4x2(const float* p, float4& a, float4& b) {
    asm volatile("global_load_dwordx4 %0, %2, off sc0 sc1\n\t"
                 "global_load_dwordx4 %1, %3, off sc0 sc1\n\t"
                 "s_waitcnt vmcnt(0)"
                 : "=&v"(a), "=&v"(b) : "v"(p), "v"(p + 4) : "memory");
}
__device__ __forceinline__ void stg_cv2(float* p, float2 v) {
    asm volatile("global_store_dwordx2 %0, %1, off sc0 sc1"
                 :: "v"(p), "v"(v) : "memory");
}

// ============================================================================
// proj2: paired input-projection GEMMs (z=0: set A, z=1: set B). tb<0 -> skip.
// ============================================================================
#define APITCH 132
#define BPITCH 132

__global__ void __launch_bounds__(256, 2)
proj2(const float* __restrict__ WA, const float* __restrict__ bihA,
      const float* __restrict__ bhhA, const float* __restrict__ XA,
      size_t sXbA, size_t sXtA, int tbA, float* __restrict__ xWA,
      const float* __restrict__ WB, const float* __restrict__ bihB,
      const float* __restrict__ bhhB, const float* __restrict__ XB,
      size_t sXbB, size_t sXtB, int tbB, float* __restrict__ xWB)
{
    const int half = blockIdx.z;
    const int tb = half ? tbB : tbA;
    if (tb < 0) return;
    const float* W   = half ? WB   : WA;
    const float* bih = half ? bihB : bihA;
    const float* bhh = half ? bhhB : bhhA;
    const float* X   = half ? XB   : XA;
    const size_t sXb = half ? sXbB : sXbA;
    const size_t sXt = half ? sXtB : sXtA;
    float* xW        = half ? xWB  : xWA;

    __shared__ float As[32][APITCH];   // [k][m]
    __shared__ float Bs[32][BPITCH];   // [k][n]
    const int tid = threadIdx.x;
    const int mbase = blockIdx.x * 128;
    const int nt = blockIdx.y;
    const int tm = tid >> 4;
    const int tn = tid & 15;
    float acc[8][8] = {};

    for (int kc = 0; kc < 512; kc += 32) {
        __syncthreads();
#pragma unroll
        for (int u = 0; u < 4; ++u) {
            const int f = u * 256 + tid;
            const int m = f >> 3, k4 = f & 7;
            const float4 v = *(const float4*)(W + (size_t)(mbase + m) * 512 + kc + k4 * 4);
            As[k4 * 4 + 0][m] = v.x; As[k4 * 4 + 1][m] = v.y;
            As[k4 * 4 + 2][m] = v.z; As[k4 * 4 + 3][m] = v.w;
        }
#pragma unroll
        for (int u = 0; u < 4; ++u) {
            const int f = u * 256 + tid;
            const int n = f >> 3, k4 = f & 7;
            const int tl = n >> 5, b = n & 31;
            const float4 v = *(const float4*)(X + (size_t)b * sXb +
                                              (size_t)(tb + nt * 4 + tl) * sXt + kc + k4 * 4);
            Bs[k4 * 4 + 0][n] = v.x; Bs[k4 * 4 + 1][n] = v.y;
            Bs[k4 * 4 + 2][n] = v.z; Bs[k4 * 4 + 3][n] = v.w;
        }
        __syncthreads();
#pragma unroll 8
        for (int kk = 0; kk < 32; ++kk) {
            const float4 a0 = *(const float4*)&As[kk][tm * 8];
            const float4 a1 = *(const float4*)&As[kk][tm * 8 + 4];
            const float4 b0 = *(const float4*)&Bs[kk][tn * 8];
            const float4 b1 = *(const float4*)&Bs[kk][tn * 8 + 4];
            const float am[8] = {a0.x,a0.y,a0.z,a0.w,a1.x,a1.y,a1.z,a1.w};
            const float bn[8] = {b0.x,b0.y,b0.z,b0.w,b1.x,b1.y,b1.z,b1.w};
#pragma unroll
            for (int i = 0; i < 8; ++i)
#pragma unroll
                for (int j = 0; j < 8; ++j)
                    acc[i][j] = fmaf(am[i], bn[j], acc[i][j]);
        }
    }
    const int tl_loc = nt * 4 + (tn >> 2);
    const int bcol = (tn & 3) * 8;
#pragma unroll
    for (int i = 0; i < 8; ++i) {
        const int m = mbase + tm * 8 + i;
        const float bias = bih[m] + bhh[m];
        float* dst = xW + ((size_t)tl_loc * 2048 + m) * 32 + bcol;
        float4 v0 = {acc[i][0] + bias, acc[i][1] + bias, acc[i][2] + bias, acc[i][3] + bias};
        float4 v1 = {acc[i][4] + bias, acc[i][5] + bias, acc[i][6] + bias, acc[i][7] + bias};
        *(float4*)dst = v0;
        *(float4*)(dst + 4) = v1;
    }
}

// ============================================================================
// lstm_recf: FUSED dual recurrence. 256 blocks x 512 threads, 1 block/CU,
//   all resident. Each block owns tile (chain = bid&7 -> 4 batches,
//   rbi = bid>>3 -> 16 hidden = 64 gate rows) of BOTH half A (layer0 chunk k)
//   and half B (layer1 chunk k-1). Per step: poll/stage A then B (one fabric
//   latency, B piggybacks), FMA A + FMA B (compute hides the other chain's
//   latency), update A on wave0 || update B on wave1.
//   Sync: R8 tagged ring (h,tag) float2 pairs, sc0sc1, depth 4, no atomics.
//   t0 < 0 -> that half inactive.
// ============================================================================
__global__ void __launch_bounds__(512, 1)
lstm_recf(const float* __restrict__ WhhA, const float* __restrict__ xWA,
          float* __restrict__ hbufA, size_t sTA, size_t sBA, int tsubA,
          float* __restrict__ cstA, float* __restrict__ ringA, int t0A,
          const float* __restrict__ WhhB, const float* __restrict__ xWB,
          float* __restrict__ hbufB, size_t sTB, size_t sBB, int tsubB,
          float* __restrict__ cstB, float* __restrict__ ringB, int t0B)
{
    __shared__ float xhA[4][512];            // 8 KB quad-swizzled h(t-1), half A
    __shared__ float xhB[4][512];            // 8 KB, half B
    __shared__ float glA[16][4][4];          // 1 KB gates A
    __shared__ float glB[16][4][4];          // 1 KB gates B

    const int tid = threadIdx.x;
    const int lb = blockIdx.x;               // 256 blocks
    const int chain = lb & 7;
    const int rbi = lb >> 3;
    const int hb = rbi * 16;                 // hidden slice [hb, hb+16)
    const int bb = chain * 4;                // batch slice [bb, bb+4)
    const bool hasA = (t0A >= 0), hasB = (t0B >= 0);

    const int rgrp = tid >> 4;               // 0..31 -> rows rgrp*2, rgrp*2+1
    const int ks = tid & 15;                 // 0..15 -> k in [ks*32, ks*32+32)
    const int ks7 = ks & 7;

    // ---- W_hh slices in registers: 2 rows x 32 k per half ----
    float wA[2][32], wB[2][32];
#pragma unroll
    for (int i = 0; i < 2; ++i) {
        const int r = rgrp * 2 + i;                       // gate g=r>>4, hl=r&15
        const int j = ((r >> 4) << 9) + hb + (r & 15);
#pragma unroll
        for (int q8 = 0; q8 < 8; ++q8) {
            if (hasA) {
                const float4 v = *(const float4*)(WhhA + (size_t)j * 512 + ks * 32 + q8 * 4);
                wA[i][q8*4+0] = v.x; wA[i][q8*4+1] = v.y;
                wA[i][q8*4+2] = v.z; wA[i][q8*4+3] = v.w;
            }
            if (hasB) {
                const float4 v = *(const float4*)(WhhB + (size_t)j * 512 + ks * 32 + q8 * 4);
                wB[i][q8*4+0] = v.x; wB[i][q8*4+1] = v.y;
                wB[i][q8*4+2] = v.z; wB[i][q8*4+3] = v.w;
            }
        }
    }
    // xwv-lane decode (ks<8): lane adds xW for (row i_x, batch b_x)
    const int i_x = ks >> 2, b_x = ks & 3;
    const int r_x = rgrp * 2 + i_x;
    const int j_x = ((r_x >> 4) << 9) + hb + (r_x & 15);
    // staging decode: batch b_s, h-quad q -> 2x16B tagged loads per half
    const int b_s = tid >> 7, q = tid & 127;
    const int swq = q ^ ((q >> 3) & 7);                  // bijective quad swizzle
    const float* rqA = ringA + ((size_t)(bb + b_s) * 512 + (q << 2)) * 2;
    const float* rqB = ringB + ((size_t)(bb + b_s) * 512 + (q << 2)) * 2;
    // update decode: wave0 (tid<64) -> half A, wave1 (tid 64..127) -> half B
    const int tidu = tid & 63;
    const int b_u = tidu >> 4, hl_u = tidu & 15;
    float c_regA = 0.0f, c_regB = 0.0f;
    if (tid < 64 && hasA)  c_regA = cstA[(size_t)(bb + b_u) * 512 + hb + hl_u];
    if (tid >= 64 && tid < 128 && hasB)
        c_regB = cstB[(size_t)(bb + b_u) * 512 + hb + hl_u];

    __syncthreads();

    for (int tl = 0; tl < TC; ++tl) {
        const int tA = t0A + tl, tB = t0B + tl;
        // prefetch precomputed input-projections (plain cached loads)
        float xwvA = 0.0f, xwvB = 0.0f;
        if (ks < 8) {
            const size_t xo = ((size_t)tl * 2048 + j_x) * 32 + bb + b_x;
            if (hasA) xwvA = xWA[xo];
            if (hasB) xwvB = xWB[xo];
        }
        // ---- phase 1: poll+stage both halves (tags travel with data) ----
        if (hasA && tA > 0) {
            const float* pA = rqA + (size_t)((tA - 1) & 3) * (32 * 512 * 2);
            const u32 tt = (u32)tA;
            float4 a0, a1;
            do { ldg_cv4x2(pA, a0, a1); }
            while (__float_as_uint(a0.y) != tt || __float_as_uint(a0.w) != tt ||
                   __float_as_uint(a1.y) != tt || __float_as_uint(a1.w) != tt);
            const float4 hq = {a0.x, a0.z, a1.x, a1.z};
            *(float4*)&xhA[b_s][swq << 2] = hq;
        }
        if (hasB && tB > 0) {
            const float* pB = rqB + (size_t)((tB - 1) & 3) * (32 * 512 * 2);
            const u32 tt = (u32)tB;
            float4 a0, a1;
            do { ldg_cv4x2(pB, a0, a1); }
            while (__float_as_uint(a0.y) != tt || __float_as_uint(a0.w) != tt ||
                   __float_as_uint(a1.y) != tt || __float_as_uint(a1.w) != tt);
            const float4 hq = {a0.x, a0.z, a1.x, a1.z};
            *(float4*)&xhB[b_s][swq << 2] = hq;
        }
        __syncthreads();                                  // xh ready

        // ---- phase 2: FMA + butterfly + gate stash, both halves ----
        float accA[2][4] = {}, accB[2][4] = {};
        if (hasA && tA > 0) {
#pragma unroll
            for (int jj = 0; jj < 8; ++jj) {
                const int sq = ((ks << 3) + (jj ^ ks7)) << 2;
                const float4 x0 = *(const float4*)&xhA[0][sq];
                const float4 x1 = *(const float4*)&xhA[1][sq];
                const float4 x2 = *(const float4*)&xhA[2][sq];
                const float4 x3 = *(const float4*)&xhA[3][sq];
#pragma unroll
                for (int i = 0; i < 2; ++i) {
                    accA[i][0] = fmaf(wA[i][jj*4+0], x0.x, accA[i][0]);
                    accA[i][0] = fmaf(wA[i][jj*4+1], x0.y, accA[i][0]);
                    accA[i][0] = fmaf(wA[i][jj*4+2], x0.z, accA[i][0]);
                    accA[i][0] = fmaf(wA[i][jj*4+3], x0.w, accA[i][0]);
                    accA[i][1] = fmaf(wA[i][jj*4+0], x1.x, accA[i][1]);
                    accA[i][1] = fmaf(wA[i][jj*4+1], x1.y, accA[i][1]);
                    accA[i][1] = fmaf(wA[i][jj*4+2], x1.z, accA[i][1]);
                    accA[i][1] = fmaf(wA[i][jj*4+3], x1.w, accA[i][1]);
                    accA[i][2] = fmaf(wA[i][jj*4+0], x2.x, accA[i][2]);
                    accA[i][2] = fmaf(wA[i][jj*4+1], x2.y, accA[i][2]);
                    accA[i][2] = fmaf(wA[i][jj*4+2], x2.z, accA[i][2]);
                    accA[i][2] = fmaf(wA[i][jj*4+3], x2.w, accA[i][2]);
                    accA[i][3] = fmaf(wA[i][jj*4+0], x3.x, accA[i][3]);
                    accA[i][3] = fmaf(wA[i][jj*4+1], x3.y, accA[i][3]);
                    accA[i][3] = fmaf(wA[i][jj*4+2], x3.z, accA[i][3]);
                    accA[i][3] = fmaf(wA[i][jj*4+3], x3.w, accA[i][3]);
                }
            }
        }
        if (hasB && tB > 0) {
#pragma unroll
            for (int jj = 0; jj < 8; ++jj) {
                const int sq = ((ks << 3) + (jj ^ ks7)) << 2;
                const float4 x0 = *(const float4*)&xhB[0][sq];
                const float4 x1 = *(const float4*)&xhB[1][sq];
                const float4 x2 = *(const float4*)&xhB[2][sq];
                const float4 x3 = *(const float4*)&xhB[3][sq];
#pragma unroll
                for (int i = 0; i < 2; ++i) {
                    accB[i][0] = fmaf(wB[i][jj*4+0], x0.x, accB[i][0]);
                    accB[i][0] = fmaf(wB[i][jj*4+1], x0.y, accB[i][0]);
                    accB[i][0] = fmaf(wB[i][jj*4+2], x0.z, accB[i][0]);
                    accB[i][0] = fmaf(wB[i][jj*4+3], x0.w, accB[i][0]);
                    accB[i][1] = fmaf(wB[i][jj*4+0], x1.x, accB[i][1]);
                    accB[i][1] = fmaf(wB[i][jj*4+1], x1.y, accB[i][1]);
                    accB[i][1] = fmaf(wB[i][jj*4+2], x1.z, accB[i][1]);
                    accB[i][1] = fmaf(wB[i][jj*4+3], x1.w, accB[i][1]);
                    accB[i][2] = fmaf(wB[i][jj*4+0], x2.x, accB[i][2]);
                    accB[i][2] = fmaf(wB[i][jj*4+1], x2.y, accB[i][2]);
                    accB[i][2] = fmaf(wB[i][jj*4+2], x2.z, accB[i][2]);
                    accB[i][2] = fmaf(wB[i][jj*4+3], x2.w, accB[i][2]);
                    accB[i][3] = fmaf(wB[i][jj*4+0], x3.x, accB[i][3]);
                    accB[i][3] = fmaf(wB[i][jj*4+1], x3.y, accB[i][3]);
                    accB[i][3] = fmaf(wB[i][jj*4+2], x3.z, accB[i][3]);
                    accB[i][3] = fmaf(wB[i][jj*4+3], x3.w, accB[i][3]);
                }
            }
        }
        if (ks < 8) { accA[i_x][b_x] += xwvA; accB[i_x][b_x] += xwvB; }
        if (hasA) {
#pragma unroll
            for (int m = 1; m < 16; m <<= 1)
#pragma unroll
                for (int i = 0; i < 2; ++i)
#pragma unroll
                    for (int b = 0; b < 4; ++b)
                        accA[i][b] += __shfl_xor(accA[i][b], m);
            if (ks == 0)
#pragma unroll
                for (int i = 0; i < 2; ++i) {
                    const int r = rgrp * 2 + i;
#pragma unroll
                    for (int b = 0; b < 4; ++b) glA[r & 15][b][r >> 4] = accA[i][b];
                }
        }
        if (hasB) {
#pragma unroll
            for (int m = 1; m < 16; m <<= 1)
#pragma unroll
                for (int i = 0; i < 2; ++i)
#pragma unroll
                    for (int b = 0; b < 4; ++b)
                        accB[i][b] += __shfl_xor(accB[i][b], m);
            if (ks == 0)
#pragma unroll
                for (int i = 0; i < 2; ++i) {
                    const int r = rgrp * 2 + i;
#pragma unroll
                    for (int b = 0; b < 4; ++b) glB[r & 15][b][r >> 4] = accB[i][b];
                }
        }
        __syncthreads();                                  // gates ready

        // ---- phase 3: cell update + publish, A on wave0 || B on wave1 ----
        if (tid < 64) {
            if (hasA) {
                const float4 gv = *(const float4*)&glA[hl_u][b_u][0];
                const float i_ = sigmoidf_(gv.x);
                const float f_ = sigmoidf_(gv.y);
                const float g_ = tanhf_(gv.z);
                const float o_ = sigmoidf_(gv.w);
                c_regA = f_ * c_regA + i_ * g_;
                const float hv = o_ * tanhf_(c_regA);
                hbufA[(size_t)(tA - tsubA) * sTA + (size_t)(bb + b_u) * sBA + hb + hl_u] = hv;
                float2 pr; pr.x = hv; pr.y = __uint_as_float((u32)(tA + 1));
                stg_cv2(ringA + ((size_t)(tA & 3) * (32 * 512) +
                                 (size_t)(bb + b_u) * 512 + hb + hl_u) * 2, pr);
            }
        } else if (tid < 128) {
            if (hasB) {
                const float4 gv = *(const float4*)&glB[hl_u][b_u][0];
                const float i_ = sigmoidf_(gv.x);
                const float f_ = sigmoidf_(gv.y);
                const float g_ = tanhf_(gv.z);
                const float o_ = sigmoidf_(gv.w);
                c_regB = f_ * c_regB + i_ * g_;
                const float hv = o_ * tanhf_(c_regB);
                hbufB[(size_t)(tB - tsubB) * sTB + (size_t)(bb + b_u) * sBB + hb + hl_u] = hv;
                float2 pr; pr.x = hv; pr.y = __uint_as_float((u32)(tB + 1));
                stg_cv2(ringB + ((size_t)(tB & 3) * (32 * 512) +
                                 (size_t)(bb + b_u) * 512 + hb + hl_u) * 2, pr);
            }
        }
        __syncthreads();
    }
    if (tid < 64 && hasA) cstA[(size_t)(bb + b_u) * 512 + hb + hl_u] = c_regA;
    if (tid >= 64 && tid < 128 && hasB)
        cstB[(size_t)(bb + b_u) * 512 + hb + hl_u] = c_regB;
}

// ============================================================================
extern "C" void kernel_launch(void* const* d_in, const int* in_sizes, int n_in,
                              void* d_out, int out_size, void* d_ws, size_t ws_size,
                              hipStream_t stream) {
    const float* inp  = (const float*)d_in[0];
    const float* Wih0 = (const float*)d_in[1];
    const float* Whh0 = (const float*)d_in[2];
    const float* bih0 = (const float*)d_in[3];
    const float* bhh0 = (const float*)d_in[4];
    const float* Wih1 = (const float*)d_in[5];
    const float* Whh1 = (const float*)d_in[6];
    const float* bih1 = (const float*)d_in[7];
    const float* bhh1 = (const float*)d_in[8];
    float* out = (float*)d_out;

    char* ws = (char*)d_ws;
    const size_t CHf = (size_t)TC * 32 * 512;               // floats per h0 chunk slot
    float* h0ring = (float*)ws;                             // 2 x [64][32][512]  8 MB
    float* xW0    = (float*)(ws + 8388608);                 // [64][2048][32]    16 MB
    float* xW1    = (float*)(ws + 25165824);                // [64][2048][32]    16 MB
    float* cst0   = (float*)(ws + 41943040);                // [32][512]        64 KB
    float* cst1   = cst0 + 32 * 512;                        //                  64 KB
    float* ring0  = (float*)(ws + 42074112);                // [4][32][512]x2  512 KB
    float* ring1  = (float*)(ws + 42598400);                // [4][32][512]x2  512 KB
    // zero c-state + rings each launch (tag epoch reset -> replay-safe)
    (void)hipMemsetAsync(ws + 41943040, 0, 131072 + 2 * 524288, stream);

    const dim3 gg(16, 16, 2), gb(256);
    const dim3 rg(256), rb(512);
    const size_t sb_in = (size_t)512 * 512;                 // inp/out batch stride
    const size_t sT_h0 = (size_t)32 * 512;                  // h0 slot t stride

    // beat k: proj { A = g0(k), B = g1(k-1) }  then  rec { A = r0(k), B = r1(k-1) }
    for (int k = 0; k <= NCHUNK; ++k) {
        const bool hasA = (k < NCHUNK);
        const bool hasB = (k >= 1);
        float* h0A    = h0ring + (size_t)(k & 1) * CHf;        // r0(k) writes slot k&1
        float* h0Bsrc = h0ring + (size_t)((k - 1) & 1) * CHf;  // g1(k-1) reads slot (k-1)&1
        hipLaunchKernelGGL(proj2, gg, gb, 0, stream,
                           Wih0, bih0, bhh0, inp, sb_in, (size_t)512,
                           hasA ? k * TC : -1, xW0,
                           Wih1, bih1, bhh1, h0Bsrc, (size_t)512, sT_h0,
                           hasB ? 0 : -1, xW1);
        hipLaunchKernelGGL(lstm_recf, rg, rb, 0, stream,
                           Whh0, xW0, h0A, sT_h0, (size_t)512, k * TC,
                           cst0, ring0, hasA ? k * TC : -1,
                           Whh1, xW1, out, (size_t)512, sb_in, 0,
                           cst1, ring1, hasB ? (k - 1) * TC : -1);
    }
}

// Round 13
// 9537.307 us; speedup vs baseline: 1.1031x; 1.1031x over previous
//
#include <hip/hip_runtime.h>
#include <stddef.h>

typedef unsigned int u32;

#define TC 64        // timestep chunk
#define NCHUNK 8

__device__ __forceinline__ float sigmoidf_(float x) {
    return 1.0f / (1.0f + __expf(-x));
}
__device__ __forceinline__ float tanhf_(float x) {
    float ax = fabsf(x);
    float e = __expf(-2.0f * ax);
    float t = (1.0f - e) / (1.0f + e);
    return copysignf(t, x);
}

// ---- per-access coherent (IF$-level) ops ----
__device__ __forceinline__ void ldg_cv4x2(const float* p, float4& a, float4& b) {
    asm volatile("global_load_dwordx4 %0, %2, off sc0 sc1\n\t"
                 "global_load_dwordx4 %1, %3, off sc0 sc1\n\t"
                 "s_waitcnt vmcnt(0)"
                 : "=&v"(a), "=&v"(b) : "v"(p), "v"(p + 4) : "memory");
}
__device__ __forceinline__ void stg_cv2(float* p, float2 v) {
    asm volatile("global_store_dwordx2 %0, %1, off sc0 sc1"
                 :: "v"(p), "v"(v) : "memory");
}

// ============================================================================
// proj2: paired input-projection GEMMs (z=0: set A, z=1: set B). tb<0 -> skip.
// ============================================================================
#define APITCH 132
#define BPITCH 132

__global__ void __launch_bounds__(256, 2)
proj2(const float* __restrict__ WA, const float* __restrict__ bihA,
      const float* __restrict__ bhhA, const float* __restrict__ XA,
      size_t sXbA, size_t sXtA, int tbA, float* __restrict__ xWA,
      const float* __restrict__ WB, const float* __restrict__ bihB,
      const float* __restrict__ bhhB, const float* __restrict__ XB,
      size_t sXbB, size_t sXtB, int tbB, float* __restrict__ xWB)
{
    const int half = blockIdx.z;
    const int tb = half ? tbB : tbA;
    if (tb < 0) return;
    const float* W   = half ? WB   : WA;
    const float* bih = half ? bihB : bihA;
    const float* bhh = half ? bhhB : bhhA;
    const float* X   = half ? XB   : XA;
    const size_t sXb = half ? sXbB : sXbA;
    const size_t sXt = half ? sXtB : sXtA;
    float* xW        = half ? xWB  : xWA;

    __shared__ float As[32][APITCH];   // [k][m]
    __shared__ float Bs[32][BPITCH];   // [k][n]
    const int tid = threadIdx.x;
    const int mbase = blockIdx.x * 128;
    const int nt = blockIdx.y;
    const int tm = tid >> 4;
    const int tn = tid & 15;
    float acc[8][8] = {};

    for (int kc = 0; kc < 512; kc += 32) {
        __syncthreads();
#pragma unroll
        for (int u = 0; u < 4; ++u) {
            const int f = u * 256 + tid;
            const int m = f >> 3, k4 = f & 7;
            const float4 v = *(const float4*)(W + (size_t)(mbase + m) * 512 + kc + k4 * 4);
            As[k4 * 4 + 0][m] = v.x; As[k4 * 4 + 1][m] = v.y;
            As[k4 * 4 + 2][m] = v.z; As[k4 * 4 + 3][m] = v.w;
        }
#pragma unroll
        for (int u = 0; u < 4; ++u) {
            const int f = u * 256 + tid;
            const int n = f >> 3, k4 = f & 7;
            const int tl = n >> 5, b = n & 31;
            const float4 v = *(const float4*)(X + (size_t)b * sXb +
                                              (size_t)(tb + nt * 4 + tl) * sXt + kc + k4 * 4);
            Bs[k4 * 4 + 0][n] = v.x; Bs[k4 * 4 + 1][n] = v.y;
            Bs[k4 * 4 + 2][n] = v.z; Bs[k4 * 4 + 3][n] = v.w;
        }
        __syncthreads();
#pragma unroll 8
        for (int kk = 0; kk < 32; ++kk) {
            const float4 a0 = *(const float4*)&As[kk][tm * 8];
            const float4 a1 = *(const float4*)&As[kk][tm * 8 + 4];
            const float4 b0 = *(const float4*)&Bs[kk][tn * 8];
            const float4 b1 = *(const float4*)&Bs[kk][tn * 8 + 4];
            const float am[8] = {a0.x,a0.y,a0.z,a0.w,a1.x,a1.y,a1.z,a1.w};
            const float bn[8] = {b0.x,b0.y,b0.z,b0.w,b1.x,b1.y,b1.z,b1.w};
#pragma unroll
            for (int i = 0; i < 8; ++i)
#pragma unroll
                for (int j = 0; j < 8; ++j)
                    acc[i][j] = fmaf(am[i], bn[j], acc[i][j]);
        }
    }
    const int tl_loc = nt * 4 + (tn >> 2);
    const int bcol = (tn & 3) * 8;
#pragma unroll
    for (int i = 0; i < 8; ++i) {
        const int m = mbase + tm * 8 + i;
        const float bias = bih[m] + bhh[m];
        float* dst = xW + ((size_t)tl_loc * 2048 + m) * 32 + bcol;
        float4 v0 = {acc[i][0] + bias, acc[i][1] + bias, acc[i][2] + bias, acc[i][3] + bias};
        float4 v1 = {acc[i][4] + bias, acc[i][5] + bias, acc[i][6] + bias, acc[i][7] + bias};
        *(float4*)dst = v0;
        *(float4*)(dst + 4) = v1;
    }
}

// ============================================================================
// lstm_recf: FUSED dual recurrence, 256 blocks x 512 threads, 1 block/CU.
//   amdgpu_waves_per_eu(2,2): pins allocator to 2 waves/EU -> 256-VGPR budget
//   (default heuristic targets 4 waves/EU and SPILLS the 128-float weight set).
//   Each block owns tile (chain = bid&7 -> 4 batches, rbi = bid>>3 -> 64 gate
//   rows) of BOTH half A (layer0 chunk k) and half B (layer1 chunk k-1).
//   Per step: JOINT poll of both rings (wait = max, not sum), FMA A + FMA B,
//   update A on wave0 || B on wave1. Tagged rings, sc0sc1, depth 4, no atomics.
// ============================================================================
__global__ void
__attribute__((amdgpu_flat_work_group_size(512, 512), amdgpu_waves_per_eu(2, 2)))
lstm_recf(const float* __restrict__ WhhA, const float* __restrict__ xWA,
          float* __restrict__ hbufA, size_t sTA, size_t sBA, int tsubA,
          float* __restrict__ cstA, float* __restrict__ ringA, int t0A,
          const float* __restrict__ WhhB, const float* __restrict__ xWB,
          float* __restrict__ hbufB, size_t sTB, size_t sBB, int tsubB,
          float* __restrict__ cstB, float* __restrict__ ringB, int t0B)
{
    __shared__ float xhA[4][512];            // 8 KB quad-swizzled h(t-1), half A
    __shared__ float xhB[4][512];            // 8 KB, half B
    __shared__ float glA[16][4][4];          // 1 KB gates A
    __shared__ float glB[16][4][4];          // 1 KB gates B

    const int tid = threadIdx.x;
    const int lb = blockIdx.x;               // 256 blocks
    const int chain = lb & 7;
    const int rbi = lb >> 3;
    const int hb = rbi * 16;                 // hidden slice [hb, hb+16)
    const int bb = chain * 4;                // batch slice [bb, bb+4)
    const bool hasA = (t0A >= 0), hasB = (t0B >= 0);

    const int rgrp = tid >> 4;               // 0..31 -> rows rgrp*2, rgrp*2+1
    const int ks = tid & 15;                 // 0..15 -> k in [ks*32, ks*32+32)
    const int ks7 = ks & 7;

    // ---- W_hh slices in registers: 2 rows x 32 k per half (128 floats) ----
    float wA[2][32], wB[2][32];
#pragma unroll
    for (int i = 0; i < 2; ++i) {
        const int r = rgrp * 2 + i;                       // gate g=r>>4, hl=r&15
        const int j = ((r >> 4) << 9) + hb + (r & 15);
#pragma unroll
        for (int q8 = 0; q8 < 8; ++q8) {
            if (hasA) {
                const float4 v = *(const float4*)(WhhA + (size_t)j * 512 + ks * 32 + q8 * 4);
                wA[i][q8*4+0] = v.x; wA[i][q8*4+1] = v.y;
                wA[i][q8*4+2] = v.z; wA[i][q8*4+3] = v.w;
            }
            if (hasB) {
                const float4 v = *(const float4*)(WhhB + (size_t)j * 512 + ks * 32 + q8 * 4);
                wB[i][q8*4+0] = v.x; wB[i][q8*4+1] = v.y;
                wB[i][q8*4+2] = v.z; wB[i][q8*4+3] = v.w;
            }
        }
    }
    // xwv-lane decode (ks<8): lane adds xW for (row i_x, batch b_x)
    const int i_x = ks >> 2, b_x = ks & 3;
    const int r_x = rgrp * 2 + i_x;
    const int j_x = ((r_x >> 4) << 9) + hb + (r_x & 15);
    // staging decode: batch b_s, h-quad q -> 2x16B tagged loads per half
    const int b_s = tid >> 7, q = tid & 127;
    const int swq = q ^ ((q >> 3) & 7);                  // bijective quad swizzle
    const float* rqA = ringA + ((size_t)(bb + b_s) * 512 + (q << 2)) * 2;
    const float* rqB = ringB + ((size_t)(bb + b_s) * 512 + (q << 2)) * 2;
    // update decode: wave0 (tid<64) -> half A, wave1 (tid 64..127) -> half B
    const int tidu = tid & 63;
    const int b_u = tidu >> 4, hl_u = tidu & 15;
    float c_regA = 0.0f, c_regB = 0.0f;
    if (tid < 64 && hasA)  c_regA = cstA[(size_t)(bb + b_u) * 512 + hb + hl_u];
    if (tid >= 64 && tid < 128 && hasB)
        c_regB = cstB[(size_t)(bb + b_u) * 512 + hb + hl_u];

    __syncthreads();

    for (int tl = 0; tl < TC; ++tl) {
        const int tA = t0A + tl, tB = t0B + tl;
        // prefetch precomputed input-projections (plain cached loads)
        float xwvA = 0.0f, xwvB = 0.0f;
        if (ks < 8) {
            const size_t xo = ((size_t)tl * 2048 + j_x) * 32 + bb + b_x;
            if (hasA) xwvA = xWA[xo];
            if (hasB) xwvB = xWB[xo];
        }
        // ---- phase 1: JOINT poll+stage of both halves (wait = max, not sum) ----
        {
            bool okA = !(hasA && tA > 0), okB = !(hasB && tB > 0);
            const float* pA = rqA + (size_t)((tA - 1) & 3) * (32 * 512 * 2);
            const float* pB = rqB + (size_t)((tB - 1) & 3) * (32 * 512 * 2);
            const u32 ttA = (u32)tA, ttB = (u32)tB;
            float4 a0, a1, b0, b1;
            while (!(okA && okB)) {
                if (!okA) {
                    ldg_cv4x2(pA, a0, a1);
                    okA = (__float_as_uint(a0.y) == ttA && __float_as_uint(a0.w) == ttA &&
                           __float_as_uint(a1.y) == ttA && __float_as_uint(a1.w) == ttA);
                }
                if (!okB) {
                    ldg_cv4x2(pB, b0, b1);
                    okB = (__float_as_uint(b0.y) == ttB && __float_as_uint(b0.w) == ttB &&
                           __float_as_uint(b1.y) == ttB && __float_as_uint(b1.w) == ttB);
                }
            }
            if (hasA && tA > 0) {
                const float4 hq = {a0.x, a0.z, a1.x, a1.z};
                *(float4*)&xhA[b_s][swq << 2] = hq;
            }
            if (hasB && tB > 0) {
                const float4 hq = {b0.x, b0.z, b1.x, b1.z};
                *(float4*)&xhB[b_s][swq << 2] = hq;
            }
        }
        __syncthreads();                                  // xh ready

        // ---- phase 2: FMA + butterfly + gate stash, both halves ----
        float accA[2][4] = {}, accB[2][4] = {};
        if (hasA && tA > 0) {
#pragma unroll
            for (int jj = 0; jj < 8; ++jj) {
                const int sq = ((ks << 3) + (jj ^ ks7)) << 2;
                const float4 x0 = *(const float4*)&xhA[0][sq];
                const float4 x1 = *(const float4*)&xhA[1][sq];
                const float4 x2 = *(const float4*)&xhA[2][sq];
                const float4 x3 = *(const float4*)&xhA[3][sq];
#pragma unroll
                for (int i = 0; i < 2; ++i) {
                    accA[i][0] = fmaf(wA[i][jj*4+0], x0.x, accA[i][0]);
                    accA[i][0] = fmaf(wA[i][jj*4+1], x0.y, accA[i][0]);
                    accA[i][0] = fmaf(wA[i][jj*4+2], x0.z, accA[i][0]);
                    accA[i][0] = fmaf(wA[i][jj*4+3], x0.w, accA[i][0]);
                    accA[i][1] = fmaf(wA[i][jj*4+0], x1.x, accA[i][1]);
                    accA[i][1] = fmaf(wA[i][jj*4+1], x1.y, accA[i][1]);
                    accA[i][1] = fmaf(wA[i][jj*4+2], x1.z, accA[i][1]);
                    accA[i][1] = fmaf(wA[i][jj*4+3], x1.w, accA[i][1]);
                    accA[i][2] = fmaf(wA[i][jj*4+0], x2.x, accA[i][2]);
                    accA[i][2] = fmaf(wA[i][jj*4+1], x2.y, accA[i][2]);
                    accA[i][2] = fmaf(wA[i][jj*4+2], x2.z, accA[i][2]);
                    accA[i][2] = fmaf(wA[i][jj*4+3], x2.w, accA[i][2]);
                    accA[i][3] = fmaf(wA[i][jj*4+0], x3.x, accA[i][3]);
                    accA[i][3] = fmaf(wA[i][jj*4+1], x3.y, accA[i][3]);
                    accA[i][3] = fmaf(wA[i][jj*4+2], x3.z, accA[i][3]);
                    accA[i][3] = fmaf(wA[i][jj*4+3], x3.w, accA[i][3]);
                }
            }
        }
        if (hasB && tB > 0) {
#pragma unroll
            for (int jj = 0; jj < 8; ++jj) {
                const int sq = ((ks << 3) + (jj ^ ks7)) << 2;
                const float4 x0 = *(const float4*)&xhB[0][sq];
                const float4 x1 = *(const float4*)&xhB[1][sq];
                const float4 x2 = *(const float4*)&xhB[2][sq];
                const float4 x3 = *(const float4*)&xhB[3][sq];
#pragma unroll
                for (int i = 0; i < 2; ++i) {
                    accB[i][0] = fmaf(wB[i][jj*4+0], x0.x, accB[i][0]);
                    accB[i][0] = fmaf(wB[i][jj*4+1], x0.y, accB[i][0]);
                    accB[i][0] = fmaf(wB[i][jj*4+2], x0.z, accB[i][0]);
                    accB[i][0] = fmaf(wB[i][jj*4+3], x0.w, accB[i][0]);
                    accB[i][1] = fmaf(wB[i][jj*4+0], x1.x, accB[i][1]);
                    accB[i][1] = fmaf(wB[i][jj*4+1], x1.y, accB[i][1]);
                    accB[i][1] = fmaf(wB[i][jj*4+2], x1.z, accB[i][1]);
                    accB[i][1] = fmaf(wB[i][jj*4+3], x1.w, accB[i][1]);
                    accB[i][2] = fmaf(wB[i][jj*4+0], x2.x, accB[i][2]);
                    accB[i][2] = fmaf(wB[i][jj*4+1], x2.y, accB[i][2]);
                    accB[i][2] = fmaf(wB[i][jj*4+2], x2.z, accB[i][2]);
                    accB[i][2] = fmaf(wB[i][jj*4+3], x2.w, accB[i][2]);
                    accB[i][3] = fmaf(wB[i][jj*4+0], x3.x, accB[i][3]);
                    accB[i][3] = fmaf(wB[i][jj*4+1], x3.y, accB[i][3]);
                    accB[i][3] = fmaf(wB[i][jj*4+2], x3.z, accB[i][3]);
                    accB[i][3] = fmaf(wB[i][jj*4+3], x3.w, accB[i][3]);
                }
            }
        }
        if (ks < 8) { accA[i_x][b_x] += xwvA; accB[i_x][b_x] += xwvB; }
#pragma unroll
        for (int m = 1; m < 16; m <<= 1)
#pragma unroll
            for (int i = 0; i < 2; ++i)
#pragma unroll
                for (int b = 0; b < 4; ++b) {
                    accA[i][b] += __shfl_xor(accA[i][b], m);
                    accB[i][b] += __shfl_xor(accB[i][b], m);
                }
        if (ks == 0) {
#pragma unroll
            for (int i = 0; i < 2; ++i) {
                const int r = rgrp * 2 + i;
#pragma unroll
                for (int b = 0; b < 4; ++b) {
                    glA[r & 15][b][r >> 4] = accA[i][b];
                    glB[r & 15][b][r >> 4] = accB[i][b];
                }
            }
        }
        __syncthreads();                                  // gates ready

        // ---- phase 3: cell update + publish, A on wave0 || B on wave1 ----
        if (tid < 64) {
            if (hasA) {
                const float4 gv = *(const float4*)&glA[hl_u][b_u][0];
                const float i_ = sigmoidf_(gv.x);
                const float f_ = sigmoidf_(gv.y);
                const float g_ = tanhf_(gv.z);
                const float o_ = sigmoidf_(gv.w);
                c_regA = f_ * c_regA + i_ * g_;
                const float hv = o_ * tanhf_(c_regA);
                hbufA[(size_t)(tA - tsubA) * sTA + (size_t)(bb + b_u) * sBA + hb + hl_u] = hv;
                float2 pr; pr.x = hv; pr.y = __uint_as_float((u32)(tA + 1));
                stg_cv2(ringA + ((size_t)(tA & 3) * (32 * 512) +
                                 (size_t)(bb + b_u) * 512 + hb + hl_u) * 2, pr);
            }
        } else if (tid < 128) {
            if (hasB) {
                const float4 gv = *(const float4*)&glB[hl_u][b_u][0];
                const float i_ = sigmoidf_(gv.x);
                const float f_ = sigmoidf_(gv.y);
                const float g_ = tanhf_(gv.z);
                const float o_ = sigmoidf_(gv.w);
                c_regB = f_ * c_regB + i_ * g_;
                const float hv = o_ * tanhf_(c_regB);
                hbufB[(size_t)(tB - tsubB) * sTB + (size_t)(bb + b_u) * sBB + hb + hl_u] = hv;
                float2 pr; pr.x = hv; pr.y = __uint_as_float((u32)(tB + 1));
                stg_cv2(ringB + ((size_t)(tB & 3) * (32 * 512) +
                                 (size_t)(bb + b_u) * 512 + hb + hl_u) * 2, pr);
            }
        }
        __syncthreads();
    }
    if (tid < 64 && hasA) cstA[(size_t)(bb + b_u) * 512 + hb + hl_u] = c_regA;
    if (tid >= 64 && tid < 128 && hasB)
        cstB[(size_t)(bb + b_u) * 512 + hb + hl_u] = c_regB;
}

// ============================================================================
extern "C" void kernel_launch(void* const* d_in, const int* in_sizes, int n_in,
                              void* d_out, int out_size, void* d_ws, size_t ws_size,
                              hipStream_t stream) {
    const float* inp  = (const float*)d_in[0];
    const float* Wih0 = (const float*)d_in[1];
    const float* Whh0 = (const float*)d_in[2];
    const float* bih0 = (const float*)d_in[3];
    const float* bhh0 = (const float*)d_in[4];
    const float* Wih1 = (const float*)d_in[5];
    const float* Whh1 = (const float*)d_in[6];
    const float* bih1 = (const float*)d_in[7];
    const float* bhh1 = (const float*)d_in[8];
    float* out = (float*)d_out;

    char* ws = (char*)d_ws;
    const size_t CHf = (size_t)TC * 32 * 512;               // floats per h0 chunk slot
    float* h0ring = (float*)ws;                             // 2 x [64][32][512]  8 MB
    float* xW0    = (float*)(ws + 8388608);                 // [64][2048][32]    16 MB
    float* xW1    = (float*)(ws + 25165824);                // [64][2048][32]    16 MB
    float* cst0   = (float*)(ws + 41943040);                // [32][512]        64 KB
    float* cst1   = cst0 + 32 * 512;                        //                  64 KB
    float* ring0  = (float*)(ws + 42074112);                // [4][32][512]x2  512 KB
    float* ring1  = (float*)(ws + 42598400);                // [4][32][512]x2  512 KB
    // zero c-state + rings each launch (tag epoch reset -> replay-safe)
    (void)hipMemsetAsync(ws + 41943040, 0, 131072 + 2 * 524288, stream);

    const dim3 gg(16, 16, 2), gb(256);
    const dim3 rg(256), rb(512);
    const size_t sb_in = (size_t)512 * 512;                 // inp/out batch stride
    const size_t sT_h0 = (size_t)32 * 512;                  // h0 slot t stride

    // beat k: proj { A = g0(k), B = g1(k-1) }  then  rec { A = r0(k), B = r1(k-1) }
    for (int k = 0; k <= NCHUNK; ++k) {
        const bool hasA = (k < NCHUNK);
        const bool hasB = (k >= 1);
        float* h0A    = h0ring + (size_t)(k & 1) * CHf;        // r0(k) writes slot k&1
        float* h0Bsrc = h0ring + (size_t)((k - 1) & 1) * CHf;  // g1(k-1) reads slot (k-1)&1
        hipLaunchKernelGGL(proj2, gg, gb, 0, stream,
                           Wih0, bih0, bhh0, inp, sb_in, (size_t)512,
                           hasA ? k * TC : -1, xW0,
                           Wih1, bih1, bhh1, h0Bsrc, (size_t)512, sT_h0,
                           hasB ? 0 : -1, xW1);
        hipLaunchKernelGGL(lstm_recf, rg, rb, 0, stream,
                           Whh0, xW0, h0A, sT_h0, (size_t)512, k * TC,
                           cst0, ring0, hasA ? k * TC : -1,
                           Whh1, xW1, out, (size_t)512, sb_in, 0,
                           cst1, ring1, hasB ? (k - 1) * TC : -1);
    }
}

// Round 14
// 5374.903 us; speedup vs baseline: 1.9573x; 1.7744x over previous
//
#include <hip/hip_runtime.h>
#include <stddef.h>

typedef unsigned int u32;

#define TC 64        // timestep chunk
#define NCHUNK 8

__device__ __forceinline__ float sigmoidf_(float x) {
    return 1.0f / (1.0f + __expf(-x));
}
__device__ __forceinline__ float tanhf_(float x) {
    float ax = fabsf(x);
    float e = __expf(-2.0f * ax);
    float t = (1.0f - e) / (1.0f + e);
    return copysignf(t, x);
}

// ---- coherent tagged poll: 8 (h,tag) pairs, one base ptr, single waitcnt ----
__device__ __forceinline__ bool poll8(const float* p, u32 tt, float4& lo, float4& hi) {
    float2 p0, p1, p2, p3, p4, p5, p6, p7;
    asm volatile(
        "global_load_dwordx2 %0, %8, off sc0 sc1\n\t"
        "global_load_dwordx2 %1, %8, off offset:8 sc0 sc1\n\t"
        "global_load_dwordx2 %2, %8, off offset:16 sc0 sc1\n\t"
        "global_load_dwordx2 %3, %8, off offset:24 sc0 sc1\n\t"
        "global_load_dwordx2 %4, %8, off offset:32 sc0 sc1\n\t"
        "global_load_dwordx2 %5, %8, off offset:40 sc0 sc1\n\t"
        "global_load_dwordx2 %6, %8, off offset:48 sc0 sc1\n\t"
        "global_load_dwordx2 %7, %8, off offset:56 sc0 sc1\n\t"
        "s_waitcnt vmcnt(0)"
        : "=&v"(p0), "=&v"(p1), "=&v"(p2), "=&v"(p3),
          "=&v"(p4), "=&v"(p5), "=&v"(p6), "=&v"(p7)
        : "v"(p) : "memory");
    const bool ok = (__float_as_uint(p0.y) == tt) & (__float_as_uint(p1.y) == tt) &
                    (__float_as_uint(p2.y) == tt) & (__float_as_uint(p3.y) == tt) &
                    (__float_as_uint(p4.y) == tt) & (__float_as_uint(p5.y) == tt) &
                    (__float_as_uint(p6.y) == tt) & (__float_as_uint(p7.y) == tt);
    lo.x = p0.x; lo.y = p1.x; lo.z = p2.x; lo.w = p3.x;
    hi.x = p4.x; hi.y = p5.x; hi.z = p6.x; hi.w = p7.x;
    return ok;
}
__device__ __forceinline__ void stg_cv2(float* p, float2 v) {
    asm volatile("global_store_dwordx2 %0, %1, off sc0 sc1"
                 :: "v"(p), "v"(v) : "memory");
}

// ============================================================================
// proj2: paired input-projection GEMMs (z=0: set A, z=1: set B). tb<0 -> skip.
// ============================================================================
#define APITCH 132
#define BPITCH 132

__global__ void __launch_bounds__(256, 2)
proj2(const float* __restrict__ WA, const float* __restrict__ bihA,
      const float* __restrict__ bhhA, const float* __restrict__ XA,
      size_t sXbA, size_t sXtA, int tbA, float* __restrict__ xWA,
      const float* __restrict__ WB, const float* __restrict__ bihB,
      const float* __restrict__ bhhB, const float* __restrict__ XB,
      size_t sXbB, size_t sXtB, int tbB, float* __restrict__ xWB)
{
    const int half = blockIdx.z;
    const int tb = half ? tbB : tbA;
    if (tb < 0) return;
    const float* W   = half ? WB   : WA;
    const float* bih = half ? bihB : bihA;
    const float* bhh = half ? bhhB : bhhA;
    const float* X   = half ? XB   : XA;
    const size_t sXb = half ? sXbB : sXbA;
    const size_t sXt = half ? sXtB : sXtA;
    float* xW        = half ? xWB  : xWA;

    __shared__ float As[32][APITCH];   // [k][m]
    __shared__ float Bs[32][BPITCH];   // [k][n]
    const int tid = threadIdx.x;
    const int mbase = blockIdx.x * 128;
    const int nt = blockIdx.y;
    const int tm = tid >> 4;
    const int tn = tid & 15;
    float acc[8][8] = {};

    for (int kc = 0; kc < 512; kc += 32) {
        __syncthreads();
#pragma unroll
        for (int u = 0; u < 4; ++u) {
            const int f = u * 256 + tid;
            const int m = f >> 3, k4 = f & 7;
            const float4 v = *(const float4*)(W + (size_t)(mbase + m) * 512 + kc + k4 * 4);
            As[k4 * 4 + 0][m] = v.x; As[k4 * 4 + 1][m] = v.y;
            As[k4 * 4 + 2][m] = v.z; As[k4 * 4 + 3][m] = v.w;
        }
#pragma unroll
        for (int u = 0; u < 4; ++u) {
            const int f = u * 256 + tid;
            const int n = f >> 3, k4 = f & 7;
            const int tl = n >> 5, b = n & 31;
            const float4 v = *(const float4*)(X + (size_t)b * sXb +
                                              (size_t)(tb + nt * 4 + tl) * sXt + kc + k4 * 4);
            Bs[k4 * 4 + 0][n] = v.x; Bs[k4 * 4 + 1][n] = v.y;
            Bs[k4 * 4 + 2][n] = v.z; Bs[k4 * 4 + 3][n] = v.w;
        }
        __syncthreads();
#pragma unroll 8
        for (int kk = 0; kk < 32; ++kk) {
            const float4 a0 = *(const float4*)&As[kk][tm * 8];
            const float4 a1 = *(const float4*)&As[kk][tm * 8 + 4];
            const float4 b0 = *(const float4*)&Bs[kk][tn * 8];
            const float4 b1 = *(const float4*)&Bs[kk][tn * 8 + 4];
            const float am[8] = {a0.x,a0.y,a0.z,a0.w,a1.x,a1.y,a1.z,a1.w};
            const float bn[8] = {b0.x,b0.y,b0.z,b0.w,b1.x,b1.y,b1.z,b1.w};
#pragma unroll
            for (int i = 0; i < 8; ++i)
#pragma unroll
                for (int j = 0; j < 8; ++j)
                    acc[i][j] = fmaf(am[i], bn[j], acc[i][j]);
        }
    }
    const int tl_loc = nt * 4 + (tn >> 2);
    const int bcol = (tn & 3) * 8;
#pragma unroll
    for (int i = 0; i < 8; ++i) {
        const int m = mbase + tm * 8 + i;
        const float bias = bih[m] + bhh[m];
        float* dst = xW + ((size_t)tl_loc * 2048 + m) * 32 + bcol;
        float4 v0 = {acc[i][0] + bias, acc[i][1] + bias, acc[i][2] + bias, acc[i][3] + bias};
        float4 v1 = {acc[i][4] + bias, acc[i][5] + bias, acc[i][6] + bias, acc[i][7] + bias};
        *(float4*)dst = v0;
        *(float4*)(dst + 4) = v1;
    }
}

// ============================================================================
// lstm_recf: FUSED dual recurrence under the 128-VGPR wall.
//   256 blocks x 512 threads. chain = bid&3 (8 batches), rbi = bid>>2
//   (8 hidden -> 32 gate rows per half). Thread (rgrp=tid>>5 -> 2 rows,
//   ks=tid&31 -> 16-wide k-slice): w[2][16] per half = 64 weight floats TOTAL.
//   Reduction: LDS transpose part[256][36] (2-way writes, floor-balanced b128
//   reads) -- no shuffle butterflies. xW folded by the update wave (4 cached
//   loads, prefetched). Sync: tagged rings (h,tag), poll8 asm, depth 4.
// ============================================================================
__global__ void __launch_bounds__(512, 1)
lstm_recf(const float* __restrict__ WhhA, const float* __restrict__ xWA,
          float* __restrict__ hbufA, size_t sTA, size_t sBA, int tsubA,
          float* __restrict__ cstA, float* __restrict__ ringA, int t0A,
          const float* __restrict__ WhhB, const float* __restrict__ xWB,
          float* __restrict__ hbufB, size_t sTB, size_t sBB, int tsubB,
          float* __restrict__ cstB, float* __restrict__ ringB, int t0B)
{
    __shared__ float xhA[8][512];        // 16 KB quad-swizzled h(t-1), half A
    __shared__ float xhB[8][512];        // 16 KB half B
    __shared__ float partA[256 * 36];    // 36 KB k-split partials A
    __shared__ float partB[256 * 36];    // 36 KB half B
    __shared__ float glA[8][8][4];       //  1 KB gates A [hl][b][g]
    __shared__ float glB[8][8][4];       //  1 KB gates B

    const int tid = threadIdx.x;
    const int chain = blockIdx.x & 3;
    const int rbi = blockIdx.x >> 2;
    const int hb = rbi * 8;              // hidden slice [hb, hb+8)
    const int bb = chain * 8;            // batch slice [bb, bb+8)
    const bool hasA = (t0A >= 0), hasB = (t0B >= 0);

    const int rgrp = tid >> 5;           // 0..15 -> rows 2rgrp, 2rgrp+1 (of 32)
    const int ks = tid & 31;             // 0..31 -> k in [ks*16, ks*16+16)

    // ---- W_hh slices in registers: 2 rows x 16 k per half (64 floats total) ----
    float wAr[2][16], wBr[2][16];
#pragma unroll
    for (int i = 0; i < 2; ++i) {
        const int r = rgrp * 2 + i;                    // row 0..31: g=r>>3, hl=r&7
        const int j = ((r >> 3) << 9) + hb + (r & 7);
#pragma unroll
        for (int q4 = 0; q4 < 4; ++q4) {
            if (hasA) {
                const float4 v = *(const float4*)(WhhA + (size_t)j * 512 + ks * 16 + q4 * 4);
                wAr[i][q4*4+0] = v.x; wAr[i][q4*4+1] = v.y;
                wAr[i][q4*4+2] = v.z; wAr[i][q4*4+3] = v.w;
            }
            if (hasB) {
                const float4 v = *(const float4*)(WhhB + (size_t)j * 512 + ks * 16 + q4 * 4);
                wBr[i][q4*4+0] = v.x; wBr[i][q4*4+1] = v.y;
                wBr[i][q4*4+2] = v.z; wBr[i][q4*4+3] = v.w;
            }
        }
    }
    // staging decode: batch b_s, 8 h at h0 (one writer block rbi = tid&63)
    const int b_s = tid >> 6;            // 0..7
    const int h0 = (tid & 63) * 8;
    const int q0 = (tid & 63) * 2;       // logical quad pair q0, q0+1
    const int s0 = q0 ^ ((q0 >> 3) & 7);
    const int s1 = (q0 + 1) ^ (((q0 + 1) >> 3) & 7);
    // update decode (wave0 -> A, wave1 -> B): 64 cells = 8 hl x 8 b
    const int tidu = tid & 63;
    const int hl_u = tidu >> 3, b_u = tidu & 7;
    float c_regA = 0.0f, c_regB = 0.0f;
    if (tid < 64 && hasA)  c_regA = cstA[(size_t)(bb + b_u) * 512 + hb + hl_u];
    if (tid >= 64 && tid < 128 && hasB)
        c_regB = cstB[(size_t)(bb + b_u) * 512 + hb + hl_u];

    __syncthreads();

    for (int tl = 0; tl < TC; ++tl) {
        const int tA = t0A + tl, tB = t0B + tl;

        // ---- update-wave xW prefetch (4 gates, plain cached loads) ----
        float xg0 = 0.f, xg1 = 0.f, xg2 = 0.f, xg3 = 0.f;
        if (tid < 64) {
            if (hasA) {
                const float* xb = xWA + ((size_t)tl * 2048 + hb + hl_u) * 32 + bb + b_u;
                xg0 = xb[0]; xg1 = xb[512 * 32]; xg2 = xb[1024 * 32]; xg3 = xb[1536 * 32];
            }
        } else if (tid < 128) {
            if (hasB) {
                const float* xb = xWB + ((size_t)tl * 2048 + hb + hl_u) * 32 + bb + b_u;
                xg0 = xb[0]; xg1 = xb[512 * 32]; xg2 = xb[1024 * 32]; xg3 = xb[1536 * 32];
            }
        }

        // ---- poll + stage h(t-1) for both halves (tags travel with data) ----
        if (hasA && tA > 0) {
            const float* pA = ringA + ((size_t)((tA - 1) & 3) * (32 * 512) +
                                       (size_t)(bb + b_s) * 512 + h0) * 2;
            float4 lo, hi;
            while (!poll8(pA, (u32)tA, lo, hi)) {}
            *(float4*)&xhA[b_s][s0 << 2] = lo;
            *(float4*)&xhA[b_s][s1 << 2] = hi;
        }
        if (hasB && tB > 0) {
            const float* pB = ringB + ((size_t)((tB - 1) & 3) * (32 * 512) +
                                       (size_t)(bb + b_s) * 512 + h0) * 2;
            float4 lo, hi;
            while (!poll8(pB, (u32)tB, lo, hi)) {}
            *(float4*)&xhB[b_s][s0 << 2] = lo;
            *(float4*)&xhB[b_s][s1 << 2] = hi;
        }
        __syncthreads();                              // xh ready

        // ---- FMA both halves (8 FMA per b128 read), partials to LDS ----
        float accA[2][8] = {};
        if (hasA && tA > 0) {
#pragma unroll
            for (int jj = 0; jj < 4; ++jj) {
                const int qq = (ks << 2) + jj;
                const int off = (qq ^ ((qq >> 3) & 7)) << 2;
#pragma unroll
                for (int b = 0; b < 8; ++b) {
                    const float4 x = *(const float4*)&xhA[b][off];
                    accA[0][b] = fmaf(wAr[0][jj*4+0], x.x, accA[0][b]);
                    accA[0][b] = fmaf(wAr[0][jj*4+1], x.y, accA[0][b]);
                    accA[0][b] = fmaf(wAr[0][jj*4+2], x.z, accA[0][b]);
                    accA[0][b] = fmaf(wAr[0][jj*4+3], x.w, accA[0][b]);
                    accA[1][b] = fmaf(wAr[1][jj*4+0], x.x, accA[1][b]);
                    accA[1][b] = fmaf(wAr[1][jj*4+1], x.y, accA[1][b]);
                    accA[1][b] = fmaf(wAr[1][jj*4+2], x.z, accA[1][b]);
                    accA[1][b] = fmaf(wAr[1][jj*4+3], x.w, accA[1][b]);
                }
            }
        }
#pragma unroll
        for (int i = 0; i < 2; ++i)
#pragma unroll
            for (int b = 0; b < 8; ++b)
                partA[(size_t)((rgrp * 2 + i) * 8 + b) * 36 + ks] = accA[i][b];

        float accB[2][8] = {};
        if (hasB && tB > 0) {
#pragma unroll
            for (int jj = 0; jj < 4; ++jj) {
                const int qq = (ks << 2) + jj;
                const int off = (qq ^ ((qq >> 3) & 7)) << 2;
#pragma unroll
                for (int b = 0; b < 8; ++b) {
                    const float4 x = *(const float4*)&xhB[b][off];
                    accB[0][b] = fmaf(wBr[0][jj*4+0], x.x, accB[0][b]);
                    accB[0][b] = fmaf(wBr[0][jj*4+1], x.y, accB[0][b]);
                    accB[0][b] = fmaf(wBr[0][jj*4+2], x.z, accB[0][b]);
                    accB[0][b] = fmaf(wBr[0][jj*4+3], x.w, accB[0][b]);
                    accB[1][b] = fmaf(wBr[1][jj*4+0], x.x, accB[1][b]);
                    accB[1][b] = fmaf(wBr[1][jj*4+1], x.y, accB[1][b]);
                    accB[1][b] = fmaf(wBr[1][jj*4+2], x.z, accB[1][b]);
                    accB[1][b] = fmaf(wBr[1][jj*4+3], x.w, accB[1][b]);
                }
            }
        }
#pragma unroll
        for (int i = 0; i < 2; ++i)
#pragma unroll
            for (int b = 0; b < 8; ++b)
                partB[(size_t)((rgrp * 2 + i) * 8 + b) * 36 + ks] = accB[i][b];
        __syncthreads();                              // partials ready

        // ---- reduce 32 k-slices: waves 0-3 -> A, waves 4-7 -> B ----
        if (tid < 256) {
            const float* row = partA + (size_t)tid * 36;
            const float4 p0 = *(const float4*)(row + 0);
            const float4 p1 = *(const float4*)(row + 4);
            const float4 p2 = *(const float4*)(row + 8);
            const float4 p3 = *(const float4*)(row + 12);
            const float4 p4 = *(const float4*)(row + 16);
            const float4 p5 = *(const float4*)(row + 20);
            const float4 p6 = *(const float4*)(row + 24);
            const float4 p7 = *(const float4*)(row + 28);
            const float s_0 = ((p0.x+p0.y)+(p0.z+p0.w)) + ((p1.x+p1.y)+(p1.z+p1.w));
            const float s_1 = ((p2.x+p2.y)+(p2.z+p2.w)) + ((p3.x+p3.y)+(p3.z+p3.w));
            const float s_2 = ((p4.x+p4.y)+(p4.z+p4.w)) + ((p5.x+p5.y)+(p5.z+p5.w));
            const float s_3 = ((p6.x+p6.y)+(p6.z+p6.w)) + ((p7.x+p7.y)+(p7.z+p7.w));
            const int r = tid >> 3, b = tid & 7;      // row 0..31, batch 0..7
            glA[r & 7][b][r >> 3] = (s_0 + s_1) + (s_2 + s_3);
        } else {
            const int o = tid - 256;
            const float* row = partB + (size_t)o * 36;
            const float4 p0 = *(const float4*)(row + 0);
            const float4 p1 = *(const float4*)(row + 4);
            const float4 p2 = *(const float4*)(row + 8);
            const float4 p3 = *(const float4*)(row + 12);
            const float4 p4 = *(const float4*)(row + 16);
            const float4 p5 = *(const float4*)(row + 20);
            const float4 p6 = *(const float4*)(row + 24);
            const float4 p7 = *(const float4*)(row + 28);
            const float s_0 = ((p0.x+p0.y)+(p0.z+p0.w)) + ((p1.x+p1.y)+(p1.z+p1.w));
            const float s_1 = ((p2.x+p2.y)+(p2.z+p2.w)) + ((p3.x+p3.y)+(p3.z+p3.w));
            const float s_2 = ((p4.x+p4.y)+(p4.z+p4.w)) + ((p5.x+p5.y)+(p5.z+p5.w));
            const float s_3 = ((p6.x+p6.y)+(p6.z+p6.w)) + ((p7.x+p7.y)+(p7.z+p7.w));
            const int r = o >> 3, b = o & 7;
            glB[r & 7][b][r >> 3] = (s_0 + s_1) + (s_2 + s_3);
        }
        __syncthreads();                              // gates ready

        // ---- cell update + publish: wave0 -> A, wave1 -> B ----
        if (tid < 64) {
            if (hasA) {
                const float4 gv = *(const float4*)&glA[hl_u][b_u][0];
                const float i_ = sigmoidf_(gv.x + xg0);
                const float f_ = sigmoidf_(gv.y + xg1);
                const float g_ = tanhf_(gv.z + xg2);
                const float o_ = sigmoidf_(gv.w + xg3);
                c_regA = f_ * c_regA + i_ * g_;
                const float hv = o_ * tanhf_(c_regA);
                hbufA[(size_t)(tA - tsubA) * sTA + (size_t)(bb + b_u) * sBA + hb + hl_u] = hv;
                float2 pr; pr.x = hv; pr.y = __uint_as_float((u32)(tA + 1));
                stg_cv2(ringA + ((size_t)(tA & 3) * (32 * 512) +
                                 (size_t)(bb + b_u) * 512 + hb + hl_u) * 2, pr);
            }
        } else if (tid < 128) {
            if (hasB) {
                const float4 gv = *(const float4*)&glB[hl_u][b_u][0];
                const float i_ = sigmoidf_(gv.x + xg0);
                const float f_ = sigmoidf_(gv.y + xg1);
                const float g_ = tanhf_(gv.z + xg2);
                const float o_ = sigmoidf_(gv.w + xg3);
                c_regB = f_ * c_regB + i_ * g_;
                const float hv = o_ * tanhf_(c_regB);
                hbufB[(size_t)(tB - tsubB) * sTB + (size_t)(bb + b_u) * sBB + hb + hl_u] = hv;
                float2 pr; pr.x = hv; pr.y = __uint_as_float((u32)(tB + 1));
                stg_cv2(ringB + ((size_t)(tB & 3) * (32 * 512) +
                                 (size_t)(bb + b_u) * 512 + hb + hl_u) * 2, pr);
            }
        }
        __syncthreads();
    }
    if (tid < 64 && hasA) cstA[(size_t)(bb + b_u) * 512 + hb + hl_u] = c_regA;
    if (tid >= 64 && tid < 128 && hasB)
        cstB[(size_t)(bb + b_u) * 512 + hb + hl_u] = c_regB;
}

// ============================================================================
extern "C" void kernel_launch(void* const* d_in, const int* in_sizes, int n_in,
                              void* d_out, int out_size, void* d_ws, size_t ws_size,
                              hipStream_t stream) {
    const float* inp  = (const float*)d_in[0];
    const float* Wih0 = (const float*)d_in[1];
    const float* Whh0 = (const float*)d_in[2];
    const float* bih0 = (const float*)d_in[3];
    const float* bhh0 = (const float*)d_in[4];
    const float* Wih1 = (const float*)d_in[5];
    const float* Whh1 = (const float*)d_in[6];
    const float* bih1 = (const float*)d_in[7];
    const float* bhh1 = (const float*)d_in[8];
    float* out = (float*)d_out;

    char* ws = (char*)d_ws;
    const size_t CHf = (size_t)TC * 32 * 512;               // floats per h0 chunk slot
    float* h0ring = (float*)ws;                             // 2 x [64][32][512]  8 MB
    float* xW0    = (float*)(ws + 8388608);                 // [64][2048][32]    16 MB
    float* xW1    = (float*)(ws + 25165824);                // [64][2048][32]    16 MB
    float* cst0   = (float*)(ws + 41943040);                // [32][512]        64 KB
    float* cst1   = cst0 + 32 * 512;                        //                  64 KB
    float* ring0  = (float*)(ws + 42074112);                // [4][32][512]x2  512 KB
    float* ring1  = (float*)(ws + 42598400);                // [4][32][512]x2  512 KB
    // zero c-state + rings each launch (tag epoch reset -> replay-safe)
    (void)hipMemsetAsync(ws + 41943040, 0, 131072 + 2 * 524288, stream);

    const dim3 gg(16, 16, 2), gb(256);
    const dim3 rg(256), rb(512);
    const size_t sb_in = (size_t)512 * 512;                 // inp/out batch stride
    const size_t sT_h0 = (size_t)32 * 512;                  // h0 slot t stride

    // beat k: proj { A = g0(k), B = g1(k-1) }  then  rec { A = r0(k), B = r1(k-1) }
    for (int k = 0; k <= NCHUNK; ++k) {
        const bool hasA = (k < NCHUNK);
        const bool hasB = (k >= 1);
        float* h0A    = h0ring + (size_t)(k & 1) * CHf;        // r0(k) writes slot k&1
        float* h0Bsrc = h0ring + (size_t)((k - 1) & 1) * CHf;  // g1(k-1) reads slot (k-1)&1
        hipLaunchKernelGGL(proj2, gg, gb, 0, stream,
                           Wih0, bih0, bhh0, inp, sb_in, (size_t)512,
                           hasA ? k * TC : -1, xW0,
                           Wih1, bih1, bhh1, h0Bsrc, (size_t)512, sT_h0,
                           hasB ? 0 : -1, xW1);
        hipLaunchKernelGGL(lstm_recf, rg, rb, 0, stream,
                           Whh0, xW0, h0A, sT_h0, (size_t)512, k * TC,
                           cst0, ring0, hasA ? k * TC : -1,
                           Whh1, xW1, out, (size_t)512, sb_in, 0,
                           cst1, ring1, hasB ? (k - 1) * TC : -1);
    }
}

// Round 15
// 4248.135 us; speedup vs baseline: 2.4765x; 1.2652x over previous
//
#include <hip/hip_runtime.h>
#include <stddef.h>

typedef unsigned int u32;
typedef __attribute__((ext_vector_type(8))) short short8;
typedef __attribute__((ext_vector_type(4))) float f32x4;

#define TC 64        // timestep chunk
#define NCHUNK 8

__device__ __forceinline__ float sigmoidf_(float x) {
    return 1.0f / (1.0f + __expf(-x));
}
__device__ __forceinline__ float tanhf_(float x) {
    float ax = fabsf(x);
    float e = __expf(-2.0f * ax);
    float t = (1.0f - e) / (1.0f + e);
    return copysignf(t, x);
}
__device__ __forceinline__ u32 cvtpk(float lo, float hi) {
    u32 r;
    asm("v_cvt_pk_bf16_f32 %0, %1, %2" : "=v"(r) : "v"(lo), "v"(hi));
    return r;
}
__device__ __forceinline__ void stg_cv1(float* p, float v) {
    asm volatile("global_store_dword %0, %1, off sc0 sc1" :: "v"(p), "v"(v) : "memory");
}
__device__ __forceinline__ void stg_cu32(u32* p, u32 v) {
    asm volatile("global_store_dword %0, %1, off sc0 sc1" :: "v"(p), "v"(v) : "memory");
}
// poll this thread's TWO producer progress words (padded stride 16 u32 = 64 B)
__device__ __forceinline__ void poll2(const u32* p, u32 tt) {
    u32 a, b;
    do {
        asm volatile("global_load_dword %0, %2, off sc0 sc1\n\t"
                     "global_load_dword %1, %2, off offset:64 sc0 sc1\n\t"
                     "s_waitcnt vmcnt(0)"
                     : "=&v"(a), "=&v"(b) : "v"(p) : "memory");
    } while (a < tt || b < tt);
}
// coherent bulk load: 32 consecutive floats (8 x dwordx4, one waitcnt)
__device__ __forceinline__ void ldg32f(const float* p,
    float4& r0, float4& r1, float4& r2, float4& r3,
    float4& r4, float4& r5, float4& r6, float4& r7) {
    asm volatile(
        "global_load_dwordx4 %0, %8, off sc0 sc1\n\t"
        "global_load_dwordx4 %1, %8, off offset:16 sc0 sc1\n\t"
        "global_load_dwordx4 %2, %8, off offset:32 sc0 sc1\n\t"
        "global_load_dwordx4 %3, %8, off offset:48 sc0 sc1\n\t"
        "global_load_dwordx4 %4, %8, off offset:64 sc0 sc1\n\t"
        "global_load_dwordx4 %5, %8, off offset:80 sc0 sc1\n\t"
        "global_load_dwordx4 %6, %8, off offset:96 sc0 sc1\n\t"
        "global_load_dwordx4 %7, %8, off offset:112 sc0 sc1\n\t"
        "s_waitcnt vmcnt(0)"
        : "=&v"(r0), "=&v"(r1), "=&v"(r2), "=&v"(r3),
          "=&v"(r4), "=&v"(r5), "=&v"(r6), "=&v"(r7)
        : "v"(p) : "memory");
}

// ============================================================================
// proj2: paired input-projection GEMMs (fp32, unchanged/proven). tb<0 -> skip.
// ============================================================================
#define APITCH 132
#define BPITCH 132

__global__ void __launch_bounds__(256, 2)
proj2(const float* __restrict__ WA, const float* __restrict__ bihA,
      const float* __restrict__ bhhA, const float* __restrict__ XA,
      size_t sXbA, size_t sXtA, int tbA, float* __restrict__ xWA,
      const float* __restrict__ WB, const float* __restrict__ bihB,
      const float* __restrict__ bhhB, const float* __restrict__ XB,
      size_t sXbB, size_t sXtB, int tbB, float* __restrict__ xWB)
{
    const int half = blockIdx.z;
    const int tb = half ? tbB : tbA;
    if (tb < 0) return;
    const float* W   = half ? WB   : WA;
    const float* bih = half ? bihB : bihA;
    const float* bhh = half ? bhhB : bhhA;
    const float* X   = half ? XB   : XA;
    const size_t sXb = half ? sXbB : sXbA;
    const size_t sXt = half ? sXtB : sXtA;
    float* xW        = half ? xWB  : xWA;

    __shared__ float As[32][APITCH];
    __shared__ float Bs[32][BPITCH];
    const int tid = threadIdx.x;
    const int mbase = blockIdx.x * 128;
    const int nt = blockIdx.y;
    const int tm = tid >> 4;
    const int tn = tid & 15;
    float acc[8][8] = {};

    for (int kc = 0; kc < 512; kc += 32) {
        __syncthreads();
#pragma unroll
        for (int u = 0; u < 4; ++u) {
            const int f = u * 256 + tid;
            const int m = f >> 3, k4 = f & 7;
            const float4 v = *(const float4*)(W + (size_t)(mbase + m) * 512 + kc + k4 * 4);
            As[k4 * 4 + 0][m] = v.x; As[k4 * 4 + 1][m] = v.y;
            As[k4 * 4 + 2][m] = v.z; As[k4 * 4 + 3][m] = v.w;
        }
#pragma unroll
        for (int u = 0; u < 4; ++u) {
            const int f = u * 256 + tid;
            const int n = f >> 3, k4 = f & 7;
            const int tl = n >> 5, b = n & 31;
            const float4 v = *(const float4*)(X + (size_t)b * sXb +
                                              (size_t)(tb + nt * 4 + tl) * sXt + kc + k4 * 4);
            Bs[k4 * 4 + 0][n] = v.x; Bs[k4 * 4 + 1][n] = v.y;
            Bs[k4 * 4 + 2][n] = v.z; Bs[k4 * 4 + 3][n] = v.w;
        }
        __syncthreads();
#pragma unroll 8
        for (int kk = 0; kk < 32; ++kk) {
            const float4 a0 = *(const float4*)&As[kk][tm * 8];
            const float4 a1 = *(const float4*)&As[kk][tm * 8 + 4];
            const float4 b0 = *(const float4*)&Bs[kk][tn * 8];
            const float4 b1 = *(const float4*)&Bs[kk][tn * 8 + 4];
            const float am[8] = {a0.x,a0.y,a0.z,a0.w,a1.x,a1.y,a1.z,a1.w};
            const float bn[8] = {b0.x,b0.y,b0.z,b0.w,b1.x,b1.y,b1.z,b1.w};
#pragma unroll
            for (int i = 0; i < 8; ++i)
#pragma unroll
                for (int j = 0; j < 8; ++j)
                    acc[i][j] = fmaf(am[i], bn[j], acc[i][j]);
        }
    }
    const int tl_loc = nt * 4 + (tn >> 2);
    const int bcol = (tn & 3) * 8;
#pragma unroll
    for (int i = 0; i < 8; ++i) {
        const int m = mbase + tm * 8 + i;
        const float bias = bih[m] + bhh[m];
        float* dst = xW + ((size_t)tl_loc * 2048 + m) * 32 + bcol;
        float4 v0 = {acc[i][0] + bias, acc[i][1] + bias, acc[i][2] + bias, acc[i][3] + bias};
        float4 v1 = {acc[i][4] + bias, acc[i][5] + bias, acc[i][6] + bias, acc[i][7] + bias};
        *(float4*)dst = v0;
        *(float4*)(dst + 4) = v1;
    }
}

// ============================================================================
// lstm_recm: MFMA recurrence. 64 blocks x 512 threads (32 per layer, disjoint
//   CUs -> layers run truly concurrently). Block = 16 hidden x ALL 32 batches.
//   Wave w: col-tile ct=w>>2 (16 batches), hidden quad h4=w&3 (4 hidden x 4
//   gates = one 16x16 D tile). Rows gate-interleaved (row = 4*hidden + gate)
//   so D lane (col=lane&15=batch, rows (lane>>4)*4+reg) = one cell's i,f,g,o.
//   A-frags = W_hh bf16 in VGPRs (16 K-chunks x 4 VGPR = 64). K=512 fully
//   accumulated by 16 MFMAs -- NO reduction. B = h(t-1) bf16 staged in LDS
//   with slot-XOR swizzle (conflict-free b128 both ways).
//   Sync: per-block progress word (padded 64B); each thread polls only its 2
//   producers; h broadcast via sc0sc1 ring, fp32.
// ============================================================================
__global__ void __launch_bounds__(512, 1)
lstm_recm(const float* __restrict__ WhhA, const float* __restrict__ xWA,
          float* __restrict__ hbufA, size_t sTA, size_t sBA, int tsubA,
          float* __restrict__ cstA, float* __restrict__ ringA,
          u32* __restrict__ progA, int t0A,
          const float* __restrict__ WhhB, const float* __restrict__ xWB,
          float* __restrict__ hbufB, size_t sTB, size_t sBB, int tsubB,
          float* __restrict__ cstB, float* __restrict__ ringB,
          u32* __restrict__ progB, int t0B)
{
    const int bid = blockIdx.x;
    const int half = bid >> 5;
    const int t0 = half ? t0B : t0A;
    if (t0 < 0) return;
    const float* Whh = half ? WhhB : WhhA;
    const float* xW  = half ? xWB  : xWA;
    float* hbuf      = half ? hbufB : hbufA;
    const size_t sT  = half ? sTB : sTA;
    const size_t sB  = half ? sBB : sBA;
    const int tsub   = half ? tsubB : tsubA;
    float* cst       = half ? cstB : cstA;
    float* ring      = half ? ringB : ringA;    // [4][32][512] fp32
    u32* prog        = half ? progB : progA;    // [32][16] padded

    __shared__ int4 xh4[32 * 64];               // h(t-1) bf16 [batch][512k], 32 KB

    const int tid = threadIdx.x;
    const int lb = bid & 31;
    const int hb = lb << 4;                     // hidden slice [hb, hb+16)
    const int w = tid >> 6, l = tid & 63;
    const int ct = w >> 2, h4 = w & 3;
    const int q = l >> 4, cl = l & 15;

    // ---- A-fragments: W_hh rows gate-interleaved, bf16, resident (64 VGPR) ----
    // lane's A-row r = cl: gate g = r&3, hidden-in-wave hp = r>>2
    const int g_a = cl & 3, hp_a = cl >> 2;
    const int jw = (g_a << 9) + hb + (h4 << 2) + hp_a;   // W_hh row
    short8 af[16];
#pragma unroll
    for (int c = 0; c < 16; ++c) {
        const float* wp = Whh + (size_t)jw * 512 + c * 32 + q * 8;
        const float4 v0 = *(const float4*)wp;
        const float4 v1 = *(const float4*)(wp + 4);
        union { short8 s; u32 wd[4]; } u;
        u.wd[0] = cvtpk(v0.x, v0.y); u.wd[1] = cvtpk(v0.z, v0.w);
        u.wd[2] = cvtpk(v1.x, v1.y); u.wd[3] = cvtpk(v1.z, v1.w);
        af[c] = u.s;
    }
    // ---- cell identity (1 cell/lane) ----
    const int hh = hb + (h4 << 2) + q;          // global hidden
    const int b  = (ct << 4) + cl;              // global batch
    float c_reg = cst[(size_t)b * 512 + hh];
    // ---- staging identity: thread -> (batch sn, 32-wide k block) ----
    const int sn = tid >> 4;
    const int sk = (tid & 15) << 5;
    const int sb4 = (tid & 15) << 2;            // slot base (16B slots of 8 bf16)
    const u32* pp = prog + ((tid & 15) << 5);   // producers 2i,2i+1 at stride 16 u32
    u32* prog_self = prog + lb * 16;

    for (int tl = 0; tl < TC; ++tl) {
        const int t = t0 + tl;
        if (t > 0) {
            poll2(pp, (u32)t);
            float4 r0, r1, r2, r3, r4, r5, r6, r7;
            ldg32f(ring + (size_t)((t - 1) & 3) * 16384 + (size_t)sn * 512 + sk,
                   r0, r1, r2, r3, r4, r5, r6, r7);
            int4 pk0, pk1, pk2, pk3;
            pk0.x = (int)cvtpk(r0.x, r0.y); pk0.y = (int)cvtpk(r0.z, r0.w);
            pk0.z = (int)cvtpk(r1.x, r1.y); pk0.w = (int)cvtpk(r1.z, r1.w);
            pk1.x = (int)cvtpk(r2.x, r2.y); pk1.y = (int)cvtpk(r2.z, r2.w);
            pk1.z = (int)cvtpk(r3.x, r3.y); pk1.w = (int)cvtpk(r3.z, r3.w);
            pk2.x = (int)cvtpk(r4.x, r4.y); pk2.y = (int)cvtpk(r4.z, r4.w);
            pk2.z = (int)cvtpk(r5.x, r5.y); pk2.w = (int)cvtpk(r5.z, r5.w);
            pk3.x = (int)cvtpk(r6.x, r6.y); pk3.y = (int)cvtpk(r6.z, r6.w);
            pk3.z = (int)cvtpk(r7.x, r7.y); pk3.w = (int)cvtpk(r7.z, r7.w);
            xh4[sn * 64 + ((sb4 + 0) ^ (sn & 7))] = pk0;
            xh4[sn * 64 + ((sb4 + 1) ^ (sn & 7))] = pk1;
            xh4[sn * 64 + ((sb4 + 2) ^ (sn & 7))] = pk2;
            xh4[sn * 64 + ((sb4 + 3) ^ (sn & 7))] = pk3;
        }
        __syncthreads();                         // xh ready (prev reads done via prev Y)

        // ---- gates: C-init from xW, then 16 MFMAs over K=512 ----
        const float* xwb = xW + ((size_t)tl * 2048 + hh) * 32 + b;
        f32x4 acc;
        acc[0] = xwb[0];
        acc[1] = xwb[512 * 32];
        acc[2] = xwb[1024 * 32];
        acc[3] = xwb[1536 * 32];
        if (t > 0) {
#pragma unroll
            for (int c = 0; c < 16; ++c) {
                const int sp = ((c << 2) + q) ^ (b & 7);
                const short8 bf = *reinterpret_cast<const short8*>(&xh4[b * 64 + sp]);
                acc = __builtin_amdgcn_mfma_f32_16x16x32_bf16(af[c], bf, acc, 0, 0, 0);
            }
        }
        // ---- lane-local cell update (D gave this lane i,f,g,o of one cell) ----
        const float i_ = sigmoidf_(acc[0]);
        const float f_ = sigmoidf_(acc[1]);
        const float g_ = tanhf_(acc[2]);
        const float o_ = sigmoidf_(acc[3]);
        c_reg = f_ * c_reg + i_ * g_;
        const float hv = o_ * tanhf_(c_reg);
        hbuf[(size_t)(t - tsub) * sT + (size_t)b * sB + hh] = hv;       // plain
        stg_cv1(ring + (size_t)(t & 3) * 16384 + (size_t)b * 512 + hh, hv);
        asm volatile("s_waitcnt vmcnt(0)" ::: "memory");
        __syncthreads();                         // Y: all lanes' stores acked
        if (tid == 0) stg_cu32(prog_self, (u32)(t + 1));
    }
    cst[(size_t)b * 512 + hh] = c_reg;
}

// ============================================================================
extern "C" void kernel_launch(void* const* d_in, const int* in_sizes, int n_in,
                              void* d_out, int out_size, void* d_ws, size_t ws_size,
                              hipStream_t stream) {
    const float* inp  = (const float*)d_in[0];
    const float* Wih0 = (const float*)d_in[1];
    const float* Whh0 = (const float*)d_in[2];
    const float* bih0 = (const float*)d_in[3];
    const float* bhh0 = (const float*)d_in[4];
    const float* Wih1 = (const float*)d_in[5];
    const float* Whh1 = (const float*)d_in[6];
    const float* bih1 = (const float*)d_in[7];
    const float* bhh1 = (const float*)d_in[8];
    float* out = (float*)d_out;

    char* ws = (char*)d_ws;
    const size_t CHf = (size_t)TC * 32 * 512;               // floats per h0 chunk slot
    float* h0ring = (float*)ws;                             // 2 x [64][32][512]  8 MB
    float* xW0    = (float*)(ws + 8388608);                 // [64][2048][32]    16 MB
    float* xW1    = (float*)(ws + 25165824);                // [64][2048][32]    16 MB
    float* cst0   = (float*)(ws + 41943040);                // [32][512]        64 KB
    float* cst1   = cst0 + 32 * 512;                        //                  64 KB
    float* ring0  = (float*)(ws + 42074112);                // [4][32][512]    256 KB
    float* ring1  = (float*)(ws + 42336256);                // [4][32][512]    256 KB
    u32*   prog0  = (u32*)  (ws + 42598400);                // [32][16]          2 KB
    u32*   prog1  = (u32*)  (ws + 42600448);                // [32][16]          2 KB
    // zero c-state + progress each launch (rings are prog-gated -> replay-safe)
    (void)hipMemsetAsync(ws + 41943040, 0, 131072 + 2 * 262144 + 4096, stream);

    const dim3 gg(16, 16, 2), gb(256);
    const dim3 rg(64), rb(512);
    const size_t sb_in = (size_t)512 * 512;
    const size_t sT_h0 = (size_t)32 * 512;

    // beat k: proj { A = g0(k), B = g1(k-1) }  then  rec { A = r0(k), B = r1(k-1) }
    for (int k = 0; k <= NCHUNK; ++k) {
        const bool hasA = (k < NCHUNK);
        const bool hasB = (k >= 1);
        float* h0A    = h0ring + (size_t)(k & 1) * CHf;
        float* h0Bsrc = h0ring + (size_t)((k - 1) & 1) * CHf;
        hipLaunchKernelGGL(proj2, gg, gb, 0, stream,
                           Wih0, bih0, bhh0, inp, sb_in, (size_t)512,
                           hasA ? k * TC : -1, xW0,
                           Wih1, bih1, bhh1, h0Bsrc, (size_t)512, sT_h0,
                           hasB ? 0 : -1, xW1);
        hipLaunchKernelGGL(lstm_recm, rg, rb, 0, stream,
                           Whh0, xW0, h0A, sT_h0, (size_t)512, k * TC,
                           cst0, ring0, prog0, hasA ? k * TC : -1,
                           Whh1, xW1, out, (size_t)512, sb_in, 0,
                           cst1, ring1, prog1, hasB ? (k - 1) * TC : -1);
    }
}